// Round 1
// baseline (452.082 us; speedup 1.0000x reference)
//
#include <hip/hip_runtime.h>
#include <hip/hip_bf16.h>

// Problem constants (setup_inputs): B=8, N=8192, S=2048, C1=128, C2=256, OUT=256
#define BB   8
#define NN   8192
#define SS   2048
#define C1C  128
#define C2C  256
#define KIN  384
#define OUTC 256

// ---------------------------------------------------------------------------
// Kernel 1: 3-NN inverse-distance interpolation of feat2 onto xyz1 points.
// One thread per query point; xyz2 (+ its squared norms) staged in LDS.
// Numerics replicate the reference gram trick d2 = n1 + n2 - 2*dot with
// explicit _rn ops (no FMA contraction) so neighbor selection matches the
// reference to ~1 ulp (tie flips would substitute an O(1)-different feature
// row and blow the absmax threshold).
// ---------------------------------------------------------------------------
__global__ __launch_bounds__(256) void knn_interp_kernel(
    const float* __restrict__ xyz1,   // (B, N, 3)
    const float* __restrict__ xyz2,   // (B, S, 3)
    const float* __restrict__ feat2,  // (B, S, C2)
    float* __restrict__ interp)       // (B, N, C2)
{
    __shared__ float sx[SS], sy[SS], sz[SS], sn2[SS];

    const int b = blockIdx.x >> 5;                       // 32 chunks of 256 per batch
    const int n = ((blockIdx.x & 31) << 8) + threadIdx.x;

    const float* x2 = xyz2 + (size_t)b * SS * 3;
    for (int i = threadIdx.x; i < SS; i += 256) {
        float qx = x2[i * 3 + 0];
        float qy = x2[i * 3 + 1];
        float qz = x2[i * 3 + 2];
        sx[i] = qx; sy[i] = qy; sz[i] = qz;
        sn2[i] = __fadd_rn(__fadd_rn(__fmul_rn(qx, qx), __fmul_rn(qy, qy)),
                           __fmul_rn(qz, qz));
    }
    __syncthreads();

    const float* p = xyz1 + ((size_t)b * NN + n) * 3;
    const float px = p[0], py = p[1], pz = p[2];
    const float n1 = __fadd_rn(__fadd_rn(__fmul_rn(px, px), __fmul_rn(py, py)),
                               __fmul_rn(pz, pz));

    float b0 = 1e30f, b1 = 1e30f, b2 = 1e30f;
    int   i0 = 0,     i1 = 0,     i2 = 0;

    for (int s = 0; s < SS; ++s) {
        float dot = __fadd_rn(__fadd_rn(__fmul_rn(px, sx[s]), __fmul_rn(py, sy[s])),
                              __fmul_rn(pz, sz[s]));
        float d2 = __fsub_rn(__fadd_rn(n1, sn2[s]), __fmul_rn(2.0f, dot));
        // strict < keeps the earlier index on exact ties (matches lax.top_k)
        bool lt2 = d2 < b2, lt1 = d2 < b1, lt0 = d2 < b0;
        b2 = lt1 ? b1 : (lt2 ? d2 : b2);
        i2 = lt1 ? i1 : (lt2 ? s  : i2);
        b1 = lt0 ? b0 : (lt1 ? d2 : b1);
        i1 = lt0 ? i0 : (lt1 ? s  : i1);
        b0 = lt0 ? d2 : b0;
        i0 = lt0 ? s  : i0;
    }

    float d0 = sqrtf(fmaxf(b0, 0.0f));
    float d1 = sqrtf(fmaxf(b1, 0.0f));
    float d2w = sqrtf(fmaxf(b2, 0.0f));
    float w0 = 1.0f / fmaxf(d0, 1e-10f);
    float w1 = 1.0f / fmaxf(d1, 1e-10f);
    float w2 = 1.0f / fmaxf(d2w, 1e-10f);
    float wsum = w0 + w1 + w2;
    w0 /= wsum; w1 /= wsum; w2 /= wsum;

    const float4* f0 = (const float4*)(feat2 + ((size_t)b * SS + i0) * C2C);
    const float4* f1 = (const float4*)(feat2 + ((size_t)b * SS + i1) * C2C);
    const float4* f2 = (const float4*)(feat2 + ((size_t)b * SS + i2) * C2C);
    float4* o = (float4*)(interp + ((size_t)b * NN + n) * C2C);

#pragma unroll 4
    for (int c = 0; c < C2C / 4; ++c) {
        float4 v0 = f0[c], v1 = f1[c], v2 = f2[c], r;
        r.x = w0 * v0.x + w1 * v1.x + w2 * v2.x;
        r.y = w0 * v0.y + w1 * v1.y + w2 * v2.y;
        r.z = w0 * v0.z + w1 * v1.z + w2 * v2.z;
        r.w = w0 * v0.w + w1 * v1.w + w2 * v2.w;
        o[c] = r;
    }
}

// ---------------------------------------------------------------------------
// Kernel 2: f32 tiled GEMM + bias + ReLU.   C = relu(A @ W + bias)
// A is (M, K) row-major, logically concat of A0 (cols [0,ks)) and A1 (rest).
// W is (K, Nn) row-major. 128x128 tile, BK=16, 256 threads, 8x8 per thread.
// sAT stored [BK][BM+4] (transposed, padded: stage-writes 2-way, reads free).
// B columns per thread split tx*4 / 64+tx*4 so ds_read_b128 stays 2-way.
// ---------------------------------------------------------------------------
#define BM 128
#define BN 128
#define BK 16

__global__ __launch_bounds__(256) void gemm_bias_relu(
    const float* __restrict__ A0, int lda0, int ks,
    const float* __restrict__ A1, int lda1,
    const float* __restrict__ W,  const float* __restrict__ bias,
    float* __restrict__ C, int K, int Nn)
{
    __shared__ __align__(16) float sAT[BK][BM + 4];
    __shared__ __align__(16) float sB[BK][BN + 4];

    const int tid = threadIdx.x;
    const int tx = tid & 15;          // 16 col-groups
    const int ty = tid >> 4;          // 16 row-groups
    const int m0 = blockIdx.x * BM;
    const int n0 = blockIdx.y * BN;

    float acc[8][8];
#pragma unroll
    for (int i = 0; i < 8; ++i)
#pragma unroll
        for (int j = 0; j < 8; ++j) acc[i][j] = 0.0f;

    for (int k0 = 0; k0 < K; k0 += BK) {
        const float* Asrc;
        int lda, kc;
        if (k0 < ks) { Asrc = A0; lda = lda0; kc = k0; }
        else         { Asrc = A1; lda = lda1; kc = k0 - ks; }

        // stage A tile (BM x BK), store transposed into sAT[c][r]
#pragma unroll
        for (int e = 0; e < 8; ++e) {
            int r = ty + 16 * e;
            sAT[tx][r] = Asrc[(size_t)(m0 + r) * lda + kc + tx];
        }
        // stage B tile (BK x BN), row-major
#pragma unroll
        for (int e = 0; e < 8; ++e) {
            int idx = tid + 256 * e;
            int r = idx >> 7, c = idx & 127;
            sB[r][c] = W[(size_t)(k0 + r) * Nn + n0 + c];
        }
        __syncthreads();

#pragma unroll
        for (int kk = 0; kk < BK; ++kk) {
            float a[8], bb[8];
            *(float4*)&a[0]  = *(const float4*)&sAT[kk][ty * 8];
            *(float4*)&a[4]  = *(const float4*)&sAT[kk][ty * 8 + 4];
            *(float4*)&bb[0] = *(const float4*)&sB[kk][tx * 4];
            *(float4*)&bb[4] = *(const float4*)&sB[kk][64 + tx * 4];
#pragma unroll
            for (int i = 0; i < 8; ++i)
#pragma unroll
                for (int j = 0; j < 8; ++j)
                    acc[i][j] = fmaf(a[i], bb[j], acc[i][j]);
        }
        __syncthreads();
    }

    // epilogue: bias + relu, cols split as tx*4 and 64+tx*4
    float bj[8];
#pragma unroll
    for (int j = 0; j < 4; ++j) {
        bj[j]     = bias[n0 + tx * 4 + j];
        bj[4 + j] = bias[n0 + 64 + tx * 4 + j];
    }
#pragma unroll
    for (int i = 0; i < 8; ++i) {
        int r = m0 + ty * 8 + i;
        float4 v0, v1;
        v0.x = fmaxf(acc[i][0] + bj[0], 0.0f);
        v0.y = fmaxf(acc[i][1] + bj[1], 0.0f);
        v0.z = fmaxf(acc[i][2] + bj[2], 0.0f);
        v0.w = fmaxf(acc[i][3] + bj[3], 0.0f);
        v1.x = fmaxf(acc[i][4] + bj[4], 0.0f);
        v1.y = fmaxf(acc[i][5] + bj[5], 0.0f);
        v1.z = fmaxf(acc[i][6] + bj[6], 0.0f);
        v1.w = fmaxf(acc[i][7] + bj[7], 0.0f);
        *(float4*)(C + (size_t)r * Nn + n0 + tx * 4)      = v0;
        *(float4*)(C + (size_t)r * Nn + n0 + 64 + tx * 4) = v1;
    }
}

// ---------------------------------------------------------------------------
// Launch: knn_interp -> interp (ws), gemm1(feat1|interp) -> H (ws),
//         gemm2(H) -> d_out.   ws usage: 2 * 67.1 MB = 128 MiB.
// ---------------------------------------------------------------------------
extern "C" void kernel_launch(void* const* d_in, const int* in_sizes, int n_in,
                              void* d_out, int out_size, void* d_ws, size_t ws_size,
                              hipStream_t stream) {
    const float* xyz1  = (const float*)d_in[0];
    const float* xyz2  = (const float*)d_in[1];
    const float* feat1 = (const float*)d_in[2];
    const float* feat2 = (const float*)d_in[3];
    const float* W1    = (const float*)d_in[4];
    const float* b1    = (const float*)d_in[5];
    const float* W2    = (const float*)d_in[6];
    const float* b2    = (const float*)d_in[7];
    float* out = (float*)d_out;

    float* interp = (float*)d_ws;                          // (B*N, C2)
    float* H      = interp + (size_t)BB * NN * C2C;        // (B*N, OUT)

    const int M = BB * NN;  // 65536

    knn_interp_kernel<<<BB * (NN / 256), 256, 0, stream>>>(xyz1, xyz2, feat2, interp);

    dim3 grid(M / BM, OUTC / BN);  // (512, 2)
    // GEMM1: A = [feat1 (cols 0..127) | interp (cols 128..383)]
    gemm_bias_relu<<<grid, 256, 0, stream>>>(feat1, C1C, C1C, interp, C2C,
                                             W1, b1, H, KIN, OUTC);
    // GEMM2: A = H only
    gemm_bias_relu<<<grid, 256, 0, stream>>>(H, OUTC, OUTC, nullptr, 0,
                                             W2, b2, out, OUTC, OUTC);
}

// Round 2
// 142.491 us; speedup vs baseline: 3.1727x; 3.1727x over previous
//
#include <hip/hip_runtime.h>
#include <hip/hip_bf16.h>

// Problem constants: B=8, N=8192, S=2048, C1=128, C2=256, OUT=256
#define BB   8
#define NN   8192
#define SS   2048
#define C1C  128
#define C2C  256
#define KIN  384
#define OUTC 256

typedef __attribute__((ext_vector_type(4))) float f32x4;
typedef __attribute__((ext_vector_type(8))) short short8;

__device__ __forceinline__ ushort f2bf(float v) {
    __hip_bfloat16 h = __float2bfloat16(v);
    return __builtin_bit_cast(ushort, h);
}

// ---------------------------------------------------------------------------
// Kernel 1: 3-NN scan. 4 lanes per query, each scans 512 of 2048 source
// points (interleaved s = 4j+t so the 4 lanes' ds_read_b128 are contiguous),
// then shfl_xor butterfly merge of per-lane top-3 with lexicographic
// (d2, idx) compare == lax.top_k stable ordering. Distance formula is the
// exact _rn sequence that passed round 1 (selection must match reference).
// ---------------------------------------------------------------------------
__global__ __launch_bounds__(256) void knn_scan_kernel(
    const float* __restrict__ xyz1, const float* __restrict__ xyz2,
    int* __restrict__ nnIdx, float* __restrict__ nnW)
{
    __shared__ float4 sp[SS];                     // (x,y,z,|p|^2), 32 KB

    const int tid = threadIdx.x;
    const int b = blockIdx.x >> 7;                // 128 blocks per batch
    const int qbase = (blockIdx.x & 127) << 6;    // 64 queries per block

    const float* x2 = xyz2 + (size_t)b * SS * 3;
    for (int i = tid; i < SS; i += 256) {
        float qx = x2[i*3+0], qy = x2[i*3+1], qz = x2[i*3+2];
        float n2 = __fadd_rn(__fadd_rn(__fmul_rn(qx,qx), __fmul_rn(qy,qy)),
                             __fmul_rn(qz,qz));
        sp[i] = make_float4(qx, qy, qz, n2);
    }
    __syncthreads();

    const int q = qbase + (tid >> 2);
    const int t = tid & 3;
    const float* p = xyz1 + ((size_t)b * NN + q) * 3;
    const float px = p[0], py = p[1], pz = p[2];
    const float n1 = __fadd_rn(__fadd_rn(__fmul_rn(px,px), __fmul_rn(py,py)),
                               __fmul_rn(pz,pz));

    float c0 = 1e30f, c1 = 1e30f, c2 = 1e30f;
    int   j0 = 0,     j1 = 0,     j2 = 0;

    for (int jj = 0; jj < SS/4; jj += 4) {
        float d2v[4]; int sv[4];
#pragma unroll
        for (int u = 0; u < 4; ++u) {
            int s = ((jj + u) << 2) + t;
            float4 P = sp[s];
            float dot = __fadd_rn(__fadd_rn(__fmul_rn(px,P.x), __fmul_rn(py,P.y)),
                                  __fmul_rn(pz,P.z));
            d2v[u] = __fsub_rn(__fadd_rn(n1, P.w), __fmul_rn(2.0f, dot));
            sv[u] = s;
        }
#pragma unroll
        for (int u = 0; u < 4; ++u) {
            float d = d2v[u];
            if (d < c2) {                          // rare: exec-mask skip
                bool lt1 = d < c1, lt0 = d < c0;
                c2 = lt1 ? c1 : d;   j2 = lt1 ? j1 : sv[u];
                c1 = lt0 ? c0 : (lt1 ? d : c1);
                j1 = lt0 ? j0 : (lt1 ? sv[u] : j1);
                c0 = lt0 ? d  : c0;  j0 = lt0 ? sv[u] : j0;
            }
        }
    }

    // butterfly merge across the 4-lane group (lex order on (d2, idx))
#pragma unroll
    for (int m = 1; m <= 2; m <<= 1) {
        float ob0 = __shfl_xor(c0, m), ob1 = __shfl_xor(c1, m), ob2 = __shfl_xor(c2, m);
        int   oj0 = __shfl_xor(j0, m), oj1 = __shfl_xor(j1, m), oj2 = __shfl_xor(j2, m);
        float dv[3] = {ob0, ob1, ob2}; int iv[3] = {oj0, oj1, oj2};
#pragma unroll
        for (int e = 0; e < 3; ++e) {
            float d = dv[e]; int s = iv[e];
            bool lt2 = (d < c2) || (d == c2 && s < j2);
            if (lt2) {
                bool lt1 = (d < c1) || (d == c1 && s < j1);
                bool lt0 = (d < c0) || (d == c0 && s < j0);
                c2 = lt1 ? c1 : d;   j2 = lt1 ? j1 : s;
                c1 = lt0 ? c0 : (lt1 ? d : c1);
                j1 = lt0 ? j0 : (lt1 ? s : j1);
                c0 = lt0 ? d  : c0;  j0 = lt0 ? s : j0;
            }
        }
    }

    float d0 = sqrtf(fmaxf(c0, 0.f));
    float d1 = sqrtf(fmaxf(c1, 0.f));
    float d2s = sqrtf(fmaxf(c2, 0.f));
    float w0 = 1.f / fmaxf(d0, 1e-10f);
    float w1 = 1.f / fmaxf(d1, 1e-10f);
    float w2 = 1.f / fmaxf(d2s, 1e-10f);
    float wsum = w0 + w1 + w2;
    w0 /= wsum; w1 /= wsum; w2 /= wsum;

    if (t == 0) {
        size_t qg = (size_t)b * NN + q;
        nnIdx[qg*3+0] = b * SS + j0;
        nnIdx[qg*3+1] = b * SS + j1;
        nnIdx[qg*3+2] = b * SS + j2;
        nnW[qg*3+0] = w0; nnW[qg*3+1] = w1; nnW[qg*3+2] = w2;
    }
}

// ---------------------------------------------------------------------------
// Kernel 2: gather+blend feat2 rows -> interp (bf16). One wave per query,
// lane covers 4 channels (float4 loads, 1 KB/row coalesced).
// ---------------------------------------------------------------------------
__global__ __launch_bounds__(256) void gather_interp_kernel(
    const float* __restrict__ feat2, const int* __restrict__ nnIdx,
    const float* __restrict__ nnW, ushort* __restrict__ interpB)
{
    const int tid = threadIdx.x;
    const int qg = blockIdx.x * 4 + (tid >> 6);
    const int lane = tid & 63;
    const int i0 = nnIdx[qg*3+0], i1 = nnIdx[qg*3+1], i2 = nnIdx[qg*3+2];
    const float w0 = nnW[qg*3+0], w1 = nnW[qg*3+1], w2 = nnW[qg*3+2];
    float4 v0 = ((const float4*)(feat2 + (size_t)i0 * C2C))[lane];
    float4 v1 = ((const float4*)(feat2 + (size_t)i1 * C2C))[lane];
    float4 v2 = ((const float4*)(feat2 + (size_t)i2 * C2C))[lane];
    ushort4 o;
    o.x = f2bf(w0*v0.x + w1*v1.x + w2*v2.x);
    o.y = f2bf(w0*v0.y + w1*v1.y + w2*v2.y);
    o.z = f2bf(w0*v0.z + w1*v1.z + w2*v2.z);
    o.w = f2bf(w0*v0.w + w1*v1.w + w2*v2.w);
    *(ushort4*)(interpB + (size_t)qg * C2C + lane * 4) = o;
}

// ---------------------------------------------------------------------------
// Prep: f32 -> bf16 convert (vectorized) and tiny transpose+convert for W.
// ---------------------------------------------------------------------------
__global__ __launch_bounds__(256) void cvt_bf16_kernel(
    const float* __restrict__ in, ushort* __restrict__ out, int n8)
{
    int i = blockIdx.x * 256 + threadIdx.x;
    if (i >= n8) return;
    const float4* p = (const float4*)in + (size_t)i * 2;
    float4 a = p[0], bq = p[1];
    ushort4 r0, r1;
    r0.x = f2bf(a.x);  r0.y = f2bf(a.y);  r0.z = f2bf(a.z);  r0.w = f2bf(a.w);
    r1.x = f2bf(bq.x); r1.y = f2bf(bq.y); r1.z = f2bf(bq.z); r1.w = f2bf(bq.w);
    ((ushort4*)out)[(size_t)i*2]   = r0;
    ((ushort4*)out)[(size_t)i*2+1] = r1;
}

__global__ __launch_bounds__(256) void transpose_cvt_kernel(
    const float* __restrict__ W, ushort* __restrict__ Wt, int K, int N)
{
    int idx = blockIdx.x * 256 + threadIdx.x;     // over N*K outputs
    if (idx >= N * K) return;
    int n = idx / K, k = idx - n * K;
    Wt[idx] = f2bf(W[(size_t)k * N + n]);
}

// ---------------------------------------------------------------------------
// bf16 MFMA GEMM (m97-ladder structure): C = relu(A @ Bt^T + bias)
// A: (M,K) bf16 row-major, column-split at ks between A0/A1.
// Bt: (N,K) bf16 row-major (pre-transposed weights).
// 128x128 tile, BK=32, 256 thr = 4 waves (2x2), each wave 64x64 via 4x4
// frags of mfma_f32_16x16x32_bf16. global_load_lds width-16 staging.
// C/D mapping (guide-verified): col = lane&15, row = (lane>>4)*4 + reg.
// ---------------------------------------------------------------------------
#define GBM 128
#define GBN 128
#define GBK 32

__device__ __forceinline__ void gld_lds16(const void* g, void* l) {
    __builtin_amdgcn_global_load_lds(
        (const __attribute__((address_space(1))) void*)g,
        (__attribute__((address_space(3))) void*)l, 16, 0, 0);
}

template<int OUT_BF16>
__global__ __launch_bounds__(256) void gemm_bt_mfma(
    const ushort* __restrict__ A0, int lda0, int ks,
    const ushort* __restrict__ A1, int lda1,
    const ushort* __restrict__ Bt, const float* __restrict__ bias,
    void* __restrict__ Cout, int M, int Nn, int K)
{
    __shared__ ushort sA[GBM * GBK];   // [128][32] row-major, 8 KB
    __shared__ ushort sB[GBN * GBK];   // [128][32] (n-major), 8 KB

    const int tid = threadIdx.x;
    const int lane = tid & 63;
    const int wid = tid >> 6;
    const int m0 = blockIdx.x * GBM;
    const int n0 = blockIdx.y * GBN;
    const int wr = wid >> 1, wc = wid & 1;

    f32x4 acc[4][4];
#pragma unroll
    for (int i = 0; i < 4; ++i)
#pragma unroll
        for (int j = 0; j < 4; ++j) acc[i][j] = (f32x4){0.f, 0.f, 0.f, 0.f};

    const int rsub = lane >> 2;          // 0..15 row within 16-row chunk
    const int csub = (lane & 3) * 8;     // 0/8/16/24 col element offset

    for (int k0 = 0; k0 < K; k0 += GBK) {
        const ushort* Asrc; int lda, kc;
        if (k0 < ks) { Asrc = A0; lda = lda0; kc = k0; }
        else         { Asrc = A1; lda = lda1; kc = k0 - ks; }

#pragma unroll
        for (int c = 0; c < 2; ++c) {
            int chunk = wid * 2 + c;                       // 0..7
            int r = chunk * 16 + rsub;
            gld_lds16(Asrc + (size_t)(m0 + r) * lda + kc + csub, &sA[chunk * 512]);
            gld_lds16(Bt   + (size_t)(n0 + r) * K   + k0 + csub, &sB[chunk * 512]);
        }
        __syncthreads();                 // compiler drains vmcnt before barrier

        short8 af[4], bf[4];
        const int kgrp = (lane >> 4) * 8;
        const int rl = lane & 15;
#pragma unroll
        for (int i = 0; i < 4; ++i) {
            af[i] = *(const short8*)&sA[(wr * 64 + i * 16 + rl) * GBK + kgrp];
            bf[i] = *(const short8*)&sB[(wc * 64 + i * 16 + rl) * GBK + kgrp];
        }
#pragma unroll
        for (int i = 0; i < 4; ++i)
#pragma unroll
            for (int j = 0; j < 4; ++j)
                acc[i][j] = __builtin_amdgcn_mfma_f32_16x16x32_bf16(
                    af[i], bf[j], acc[i][j], 0, 0, 0);
        __syncthreads();
    }

    const int cl = lane & 15;
    const int rgrp = (lane >> 4) * 4;
#pragma unroll
    for (int j = 0; j < 4; ++j) {
        int col = n0 + wc * 64 + j * 16 + cl;
        float bv = bias[col];
#pragma unroll
        for (int i = 0; i < 4; ++i) {
            int rowb = m0 + wr * 64 + i * 16 + rgrp;
#pragma unroll
            for (int r = 0; r < 4; ++r) {
                float v = fmaxf(acc[i][j][r] + bv, 0.f);
                if constexpr (OUT_BF16)
                    ((ushort*)Cout)[(size_t)(rowb + r) * Nn + col] = f2bf(v);
                else
                    ((float*)Cout)[(size_t)(rowb + r) * Nn + col] = v;
            }
        }
    }
}

// ---------------------------------------------------------------------------
// Launch. ws layout (bytes):
//   interpB 33.5M | featB 16.8M | HB 33.5M | W1t 192K | W2t 128K
//   | nnIdx 768K | nnW 768K   (total ~85.8 MB)
// ---------------------------------------------------------------------------
extern "C" void kernel_launch(void* const* d_in, const int* in_sizes, int n_in,
                              void* d_out, int out_size, void* d_ws, size_t ws_size,
                              hipStream_t stream) {
    const float* xyz1  = (const float*)d_in[0];
    const float* xyz2  = (const float*)d_in[1];
    const float* feat1 = (const float*)d_in[2];
    const float* feat2 = (const float*)d_in[3];
    const float* W1    = (const float*)d_in[4];
    const float* b1    = (const float*)d_in[5];
    const float* W2    = (const float*)d_in[6];
    const float* b2    = (const float*)d_in[7];
    float* out = (float*)d_out;

    char* ws = (char*)d_ws;
    ushort* interpB = (ushort*)(ws);
    ushort* featB   = (ushort*)(ws + 33554432);
    ushort* HB      = (ushort*)(ws + 50331648);
    ushort* W1t     = (ushort*)(ws + 83886080);
    ushort* W2t     = (ushort*)(ws + 84082688);
    int*    nnIdx   = (int*)  (ws + 84213760);
    float*  nnW     = (float*)(ws + 85000192);

    const int M = BB * NN;  // 65536

    cvt_bf16_kernel<<<(M * C1C / 8) / 256, 256, 0, stream>>>(feat1, featB, M * C1C / 8);
    transpose_cvt_kernel<<<(KIN * OUTC + 255) / 256, 256, 0, stream>>>(W1, W1t, KIN, OUTC);
    transpose_cvt_kernel<<<(OUTC * OUTC + 255) / 256, 256, 0, stream>>>(W2, W2t, OUTC, OUTC);

    knn_scan_kernel<<<BB * (NN / 64), 256, 0, stream>>>(xyz1, xyz2, nnIdx, nnW);
    gather_interp_kernel<<<M / 4, 256, 0, stream>>>(feat2, nnIdx, nnW, interpB);

    dim3 grid(M / GBM, OUTC / GBN);  // (512, 2)
    gemm_bt_mfma<1><<<grid, 256, 0, stream>>>(featB, C1C, C1C, interpB, C2C,
                                              W1t, b1, HB, M, OUTC, KIN);
    gemm_bt_mfma<0><<<grid, 256, 0, stream>>>(HB, OUTC, OUTC, nullptr, 0,
                                              W2t, b2, out, M, OUTC, OUTC);
}